// Round 2
// baseline (1714.725 us; speedup 1.0000x reference)
//
#include <hip/hip_runtime.h>

#define NUM_USERS 100000
#define NUM_ITEMS 50000
#define IN_DIM 128
#define HID_DIM 256
#define OUT_DIM 64
#define R_LEVELS 5
#define NEDGE 300000
#define EPSC 1e-10f

// ---------------------------------------------------------------------------
// Kernel A: fuse per-rating message weight with output weight:
//   Wc[r] = W1[r] (128x256) @ Wout (256x64)  -> (128x64)
// blockIdx.x = r*IN_DIM + k  (row),  blockIdx.y = direction (0=user,1=item)
// threadIdx.x = j (output col, 64 threads)
// ---------------------------------------------------------------------------
__global__ void fuse_weights(const float* __restrict__ W_i2u,
                             const float* __restrict__ W_u2i,
                             const float* __restrict__ Wout_u,
                             const float* __restrict__ Wout_i,
                             float* __restrict__ Wc_u,
                             float* __restrict__ Wc_v) {
    const int rk = blockIdx.x;          // 0 .. R*IN_DIM-1
    const int j  = threadIdx.x;         // 0 .. 63
    const bool userDir = (blockIdx.y == 0);
    const float* w1   = (userDir ? W_i2u : W_u2i) + (size_t)rk * HID_DIM;
    const float* wout = (userDir ? Wout_u : Wout_i);
    float acc = 0.f;
    for (int h = 0; h < HID_DIM; ++h)
        acc = fmaf(w1[h], wout[h * OUT_DIM + j], acc);
    float* dst = (userDir ? Wc_u : Wc_v);
    dst[(size_t)rk * OUT_DIM + j] = acc;
}

// ---------------------------------------------------------------------------
// Kernel B: per-edge fused transform + scatter.
// One wave = one edge at a time. lane j owns output dim j and keeps the
// 128-entry Wc column in registers. X row broadcast via per-wave LDS buffer
// (wave-synchronous — DS ops from one wave complete in order, no block
// barrier needed). 64 coalesced atomic f32 adds per edge.
// grid: (CHUNKS, R_LEVELS, 2)   block: 256 (4 waves)
// ---------------------------------------------------------------------------
__global__ __launch_bounds__(256, 2)
void edge_scatter(const int*   __restrict__ u_idx,
                  const int*   __restrict__ v_idx,
                  const float* __restrict__ deg_user,
                  const float* __restrict__ deg_item,
                  const float* __restrict__ X_u,
                  const float* __restrict__ X_v,
                  const float* __restrict__ Wc_u,
                  const float* __restrict__ Wc_v,
                  float*       __restrict__ out) {
    __shared__ float xbuf[4][IN_DIM];

    const int r    = blockIdx.y;
    const int wave = threadIdx.x >> 6;
    const int lane = threadIdx.x & 63;
    const bool toUser = (blockIdx.z == 0);

    const int*   dI   = (toUser ? u_idx : v_idx) + (size_t)r * NEDGE;
    const int*   sI   = (toUser ? v_idx : u_idx) + (size_t)r * NEDGE;
    const float* degD = toUser ? deg_user : deg_item;
    const float* degS = toUser ? deg_item : deg_user;
    const float* Xs   = toUser ? X_v : X_u;
    const float* Wc   = (toUser ? Wc_u : Wc_v) + (size_t)r * IN_DIM * OUT_DIM;
    float*       outp = out + (toUser ? 0 : (size_t)NUM_USERS * OUT_DIM);

    // Wc column j for this rating into registers (128 VGPRs)
    float wc[IN_DIM];
#pragma unroll
    for (int k = 0; k < IN_DIM; ++k)
        wc[k] = Wc[(size_t)k * OUT_DIM + lane];

    float2* xb2 = (float2*)xbuf[wave];
    const float4* xq = (const float4*)xbuf[wave];

    int e = blockIdx.x * 4 + wave;
    const int estride = gridDim.x * 4;

#pragma unroll 1
    for (; e < NEDGE; e += estride) {
        const int d = dI[e];              // wave-uniform
        const int s = sI[e];
        const float nd = degD[d];
        const float ns = degS[s];
        const float norm = 1.0f / (sqrtf(fmaxf(nd, EPSC)) * sqrtf(fmaxf(ns, EPSC)));

        // coalesced 512B row load, stage to per-wave LDS for broadcast
        const float2 xv = ((const float2*)(Xs + (size_t)s * IN_DIM))[lane];
        xb2[lane] = xv;
        __builtin_amdgcn_wave_barrier();   // keep LDS write before reads

        float y0 = 0.f, y1 = 0.f, y2 = 0.f, y3 = 0.f;
#pragma unroll
        for (int k4 = 0; k4 < IN_DIM / 4; ++k4) {
            const float4 q = xq[k4];       // broadcast ds_read_b128
            y0 = fmaf(q.x, wc[4 * k4 + 0], y0);
            y1 = fmaf(q.y, wc[4 * k4 + 1], y1);
            y2 = fmaf(q.z, wc[4 * k4 + 2], y2);
            y3 = fmaf(q.w, wc[4 * k4 + 3], y3);
        }
        __builtin_amdgcn_wave_barrier();   // reads done before next iter's write

        const float y = ((y0 + y1) + (y2 + y3)) * norm;
        atomicAdd(outp + (size_t)d * OUT_DIM + lane, y);
    }
}

// ---------------------------------------------------------------------------
// Kernel C: in-place bias + ReLU epilogue over the concatenated output
// ---------------------------------------------------------------------------
__global__ void bias_relu(float* __restrict__ out,
                          const float* __restrict__ b_u,
                          const float* __restrict__ b_v) {
    const size_t i = (size_t)blockIdx.x * 256 + threadIdx.x;
    constexpr size_t UOUT = (size_t)NUM_USERS * OUT_DIM;
    constexpr size_t TOT  = UOUT + (size_t)NUM_ITEMS * OUT_DIM;
    if (i < TOT) {
        const float b = (i < UOUT) ? b_u[i & 63] : b_v[i & 63];
        out[i] = fmaxf(out[i] + b, 0.f);
    }
}

// ---------------------------------------------------------------------------
extern "C" void kernel_launch(void* const* d_in, const int* in_sizes, int n_in,
                              void* d_out, int out_size, void* d_ws, size_t ws_size,
                              hipStream_t stream) {
    const int*   u_idx    = (const int*)  d_in[0];
    const int*   v_idx    = (const int*)  d_in[1];
    const float* deg_user = (const float*)d_in[2];
    const float* deg_item = (const float*)d_in[3];
    const float* X_u      = (const float*)d_in[4];
    const float* X_v      = (const float*)d_in[5];
    const float* W_i2u    = (const float*)d_in[6];
    const float* W_u2i    = (const float*)d_in[7];
    const float* W_out_u  = (const float*)d_in[8];
    const float* b_out_u  = (const float*)d_in[9];
    const float* W_out_i  = (const float*)d_in[10];
    const float* b_out_i  = (const float*)d_in[11];

    float* out  = (float*)d_out;
    float* Wc_u = (float*)d_ws;                                   // [5,128,64]
    float* Wc_v = Wc_u + (size_t)R_LEVELS * IN_DIM * OUT_DIM;     // [5,128,64]

    // zero the accumulator (harness poisons d_out with 0xAA)
    hipMemsetAsync(d_out, 0, (size_t)out_size * sizeof(float), stream);

    // fold W_msg @ W_out -> Wc (tiny)
    fuse_weights<<<dim3(R_LEVELS * IN_DIM, 2), 64, 0, stream>>>(
        W_i2u, W_u2i, W_out_u, W_out_i, Wc_u, Wc_v);

    // fused gather -> 64-dim transform -> scatter-add for both directions
    edge_scatter<<<dim3(120, R_LEVELS, 2), 256, 0, stream>>>(
        u_idx, v_idx, deg_user, deg_item, X_u, X_v, Wc_u, Wc_v, out);

    // epilogue
    const size_t total = (size_t)NUM_USERS * OUT_DIM + (size_t)NUM_ITEMS * OUT_DIM;
    bias_relu<<<(int)((total + 255) / 256), 256, 0, stream>>>(out, b_out_u, b_out_i);
}

// Round 5
// 808.322 us; speedup vs baseline: 2.1213x; 2.1213x over previous
//
#include <hip/hip_runtime.h>
#include <hip/hip_bf16.h>

#define NUM_USERS 100000
#define NUM_ITEMS 50000
#define IN_DIM 128
#define HID_DIM 256
#define OUT_DIM 64
#define R_LEVELS 5
#define NEDGE 300000
#define EPSC 1e-10f

typedef float f32x4 __attribute__((ext_vector_type(4)));
typedef short s16x8 __attribute__((ext_vector_type(8)));

static __device__ __forceinline__ short f2bf(float f) {
    __hip_bfloat16 h = __float2bfloat16(f);   // RNE
    return *reinterpret_cast<short*>(&h);
}

// ---------------------------------------------------------------------------
// Kernel A: Wc[r] = W1[r] (128x256) @ Wout (256x64), stored TRANSPOSED as
// bf16: WcT[r][n (64)][k (128)] so an MFMA B-fragment (8 consecutive k at
// fixed n) is one 16B load.
// grid: (R*128, 2), block: 64  (thread j = output col)
// ---------------------------------------------------------------------------
__global__ void fuse_weights(const float* __restrict__ W_i2u,
                             const float* __restrict__ W_u2i,
                             const float* __restrict__ Wout_u,
                             const float* __restrict__ Wout_i,
                             unsigned short* __restrict__ WcT_u,
                             unsigned short* __restrict__ WcT_v) {
    const int rk = blockIdx.x;          // r*128 + k
    const int r  = rk >> 7;
    const int k  = rk & 127;
    const int j  = threadIdx.x;         // 0..63
    const bool userDir = (blockIdx.y == 0);
    const float* w1   = (userDir ? W_i2u : W_u2i) + (size_t)rk * HID_DIM;
    const float* wout = (userDir ? Wout_u : Wout_i);
    float acc = 0.f;
    for (int h = 0; h < HID_DIM; ++h)
        acc = fmaf(w1[h], wout[h * OUT_DIM + j], acc);
    unsigned short* dst = (userDir ? WcT_u : WcT_v);
    dst[(((size_t)r * OUT_DIM + j) * IN_DIM) + k] = (unsigned short)f2bf(acc);
}

// ---------------------------------------------------------------------------
// Kernel B: MFMA edge transform + scatter.
// One wave processes 16 edges/chunk: A = norm-scaled X rows [16x128] bf16
// (gathered per-lane from global), B = WcT fragments (held in 64 VGPRs),
// C = [16 x 64] f32 -> 64 atomic f32 adds per edge (16-lane coalesced).
// mfma_f32_16x16x32_bf16 operand layout:
//   A: row = lane&15,              k = (lane>>4)*8 + i
//   B: col = lane&15,              k = (lane>>4)*8 + i
//   C: col = lane&15,            row = (lane>>4)*4 + reg   (m89-verified)
// grid: (G, R_LEVELS, 2)  block: 256 (4 waves)
// ---------------------------------------------------------------------------
__global__ __launch_bounds__(256)
void edge_mfma(const int*   __restrict__ u_idx,
               const int*   __restrict__ v_idx,
               const float* __restrict__ deg_user,
               const float* __restrict__ deg_item,
               const float* __restrict__ X_u,
               const float* __restrict__ X_v,
               const unsigned short* __restrict__ WcT_u,
               const unsigned short* __restrict__ WcT_v,
               float*       __restrict__ out) {
    const int r    = blockIdx.y;
    const bool toUser = (blockIdx.z == 0);
    const int lane = threadIdx.x & 63;
    const int wave = threadIdx.x >> 6;
    const int m    = lane & 15;       // row-in-tile / output col-in-tile
    const int g    = lane >> 4;       // 16-lane group 0..3

    const int*   dI   = (toUser ? u_idx : v_idx) + (size_t)r * NEDGE;
    const int*   sI   = (toUser ? v_idx : u_idx) + (size_t)r * NEDGE;
    const float* degD = toUser ? deg_user : deg_item;
    const float* degS = toUser ? deg_item : deg_user;
    const float* Xs   = toUser ? X_v : X_u;
    const unsigned short* WcT = (toUser ? WcT_u : WcT_v) + (size_t)r * OUT_DIM * IN_DIM;
    float*       outp = out + (toUser ? 0 : (size_t)NUM_USERS * OUT_DIM);

    // B fragments: nt = n-tile (n = nt*16 + m), ks = K-step (k = ks*32 + g*8 + i)
    s16x8 bfrag[4][4];
#pragma unroll
    for (int nt = 0; nt < 4; ++nt)
#pragma unroll
        for (int ks = 0; ks < 4; ++ks)
            bfrag[nt][ks] = *reinterpret_cast<const s16x8*>(
                WcT + ((size_t)(nt * 16 + m) * IN_DIM + ks * 32 + g * 8));

    const int wid     = blockIdx.x * 4 + wave;
    const int wstride = gridDim.x * 4;
    constexpr int NCHUNK = NEDGE / 16;   // 18750

    for (int c = wid; c < NCHUNK; c += wstride) {
        const int e0 = c * 16;
        // per-row (m) source + norm; lanes m, m+16, m+32, m+48 redundant (L1 broadcast)
        const int   sS  = sI[e0 + m];
        const int   dDm = dI[e0 + m];
        const float norm = 1.0f / (sqrtf(fmaxf(degD[dDm], EPSC)) *
                                   sqrtf(fmaxf(degS[sS],  EPSC)));
        const float* xrow = Xs + (size_t)sS * IN_DIM;

        // A fragments: lane reads 8 consecutive f32 of its row-chunk, scales, cvt bf16
        s16x8 afrag[4];
#pragma unroll
        for (int ks = 0; ks < 4; ++ks) {
            const float4 q0 = *reinterpret_cast<const float4*>(xrow + ks * 32 + g * 8);
            const float4 q1 = *reinterpret_cast<const float4*>(xrow + ks * 32 + g * 8 + 4);
            s16x8 av;
            av[0] = f2bf(q0.x * norm); av[1] = f2bf(q0.y * norm);
            av[2] = f2bf(q0.z * norm); av[3] = f2bf(q0.w * norm);
            av[4] = f2bf(q1.x * norm); av[5] = f2bf(q1.y * norm);
            av[6] = f2bf(q1.z * norm); av[7] = f2bf(q1.w * norm);
            afrag[ks] = av;
        }

        // dest indices for the C rows this lane will write (row = g*4 + i)
        int dd[4];
#pragma unroll
        for (int i = 0; i < 4; ++i) dd[i] = dI[e0 + g * 4 + i];

#pragma unroll
        for (int nt = 0; nt < 4; ++nt) {
            f32x4 acc = {0.f, 0.f, 0.f, 0.f};
#pragma unroll
            for (int ks = 0; ks < 4; ++ks)
                acc = __builtin_amdgcn_mfma_f32_16x16x32_bf16(
                    afrag[ks], bfrag[nt][ks], acc, 0, 0, 0);
#pragma unroll
            for (int i = 0; i < 4; ++i)
                atomicAdd(outp + (size_t)dd[i] * OUT_DIM + nt * 16 + m, acc[i]);
        }
    }
}

// ---------------------------------------------------------------------------
// Kernel C: in-place bias + ReLU epilogue
// ---------------------------------------------------------------------------
__global__ void bias_relu(float* __restrict__ out,
                          const float* __restrict__ b_u,
                          const float* __restrict__ b_v) {
    const size_t i = (size_t)blockIdx.x * 256 + threadIdx.x;
    constexpr size_t UOUT = (size_t)NUM_USERS * OUT_DIM;
    constexpr size_t TOT  = UOUT + (size_t)NUM_ITEMS * OUT_DIM;
    if (i < TOT) {
        const float b = (i < UOUT) ? b_u[i & 63] : b_v[i & 63];
        out[i] = fmaxf(out[i] + b, 0.f);
    }
}

// ---------------------------------------------------------------------------
extern "C" void kernel_launch(void* const* d_in, const int* in_sizes, int n_in,
                              void* d_out, int out_size, void* d_ws, size_t ws_size,
                              hipStream_t stream) {
    const int*   u_idx    = (const int*)  d_in[0];
    const int*   v_idx    = (const int*)  d_in[1];
    const float* deg_user = (const float*)d_in[2];
    const float* deg_item = (const float*)d_in[3];
    const float* X_u      = (const float*)d_in[4];
    const float* X_v      = (const float*)d_in[5];
    const float* W_i2u    = (const float*)d_in[6];
    const float* W_u2i    = (const float*)d_in[7];
    const float* W_out_u  = (const float*)d_in[8];
    const float* b_out_u  = (const float*)d_in[9];
    const float* W_out_i  = (const float*)d_in[10];
    const float* b_out_i  = (const float*)d_in[11];

    float* out  = (float*)d_out;
    unsigned short* WcT_u = (unsigned short*)d_ws;                        // [5][64][128] bf16
    unsigned short* WcT_v = WcT_u + (size_t)R_LEVELS * OUT_DIM * IN_DIM;  // [5][64][128] bf16

    // zero the accumulator (harness poisons d_out with 0xAA)
    hipMemsetAsync(d_out, 0, (size_t)out_size * sizeof(float), stream);

    // fold W_msg @ W_out -> WcT (bf16, transposed for B-fragment loads)
    fuse_weights<<<dim3(R_LEVELS * IN_DIM, 2), 64, 0, stream>>>(
        W_i2u, W_u2i, W_out_u, W_out_i, WcT_u, WcT_v);

    // MFMA gather -> 16x128 @ 128x64 -> scatter-add, both directions
    edge_mfma<<<dim3(128, R_LEVELS, 2), 256, 0, stream>>>(
        u_idx, v_idx, deg_user, deg_item, X_u, X_v, WcT_u, WcT_v, out);

    // epilogue
    const size_t total = (size_t)NUM_USERS * OUT_DIM + (size_t)NUM_ITEMS * OUT_DIM;
    bias_relu<<<(int)((total + 255) / 256), 256, 0, stream>>>(out, b_out_u, b_out_i);
}

// Round 6
// 800.035 us; speedup vs baseline: 2.1433x; 1.0104x over previous
//
#include <hip/hip_runtime.h>
#include <hip/hip_bf16.h>

#define NUM_USERS 100000
#define NUM_ITEMS 50000
#define IN_DIM 128
#define HID_DIM 256
#define OUT_DIM 64
#define R_LEVELS 5
#define NEDGE 300000
#define EPSC 1e-10f

typedef float f32x4 __attribute__((ext_vector_type(4)));
typedef short s16x8 __attribute__((ext_vector_type(8)));

static __device__ __forceinline__ unsigned short f2bf(float f) {
    __hip_bfloat16 h = __float2bfloat16(f);   // RNE
    return *reinterpret_cast<unsigned short*>(&h);
}

// ---------------------------------------------------------------------------
// Kernel A: WcT[r][n][k] = (W1[r] @ Wout)^T in bf16 (B-fragment = one 16B load)
// grid: (R*128, 2), block 64
// ---------------------------------------------------------------------------
__global__ void fuse_weights(const float* __restrict__ W_i2u,
                             const float* __restrict__ W_u2i,
                             const float* __restrict__ Wout_u,
                             const float* __restrict__ Wout_i,
                             unsigned short* __restrict__ WcT_u,
                             unsigned short* __restrict__ WcT_v) {
    const int rk = blockIdx.x;          // r*128 + k
    const int r  = rk >> 7;
    const int k  = rk & 127;
    const int j  = threadIdx.x;         // 0..63
    const bool userDir = (blockIdx.y == 0);
    const float* w1   = (userDir ? W_i2u : W_u2i) + (size_t)rk * HID_DIM;
    const float* wout = (userDir ? Wout_u : Wout_i);
    float acc = 0.f;
    for (int h = 0; h < HID_DIM; ++h)
        acc = fmaf(w1[h], wout[h * OUT_DIM + j], acc);
    unsigned short* dst = (userDir ? WcT_u : WcT_v);
    dst[(((size_t)r * OUT_DIM + j) * IN_DIM) + k] = f2bf(acc);
}

// ---------------------------------------------------------------------------
// Kernel P: pre-scale X rows by rsq(own degree), convert to bf16; also emit
// rsq[] for the dest-side epilogue scale. One wave per row (lane holds 2 f32).
// ---------------------------------------------------------------------------
__global__ void prescale_rows(const float* __restrict__ X,
                              const float* __restrict__ deg,
                              unsigned short* __restrict__ Xn,
                              float* __restrict__ rsq, int nrows) {
    const int row = blockIdx.x * 4 + (threadIdx.x >> 6);
    if (row >= nrows) return;
    const int lane = threadIdx.x & 63;
    const float r = 1.0f / sqrtf(fmaxf(deg[row], EPSC));
    if (lane == 0) rsq[row] = r;
    const float2 x = ((const float2*)(X + (size_t)row * IN_DIM))[lane];
    const unsigned int packed = (unsigned int)f2bf(x.x * r) |
                                ((unsigned int)f2bf(x.y * r) << 16);
    ((unsigned int*)(Xn + (size_t)row * IN_DIM))[lane] = packed;
}

// ---------------------------------------------------------------------------
// Kernel B (fast): MFMA edge transform + scatter, pre-scaled bf16 X.
// Per-chunk chain: sI load -> bf16 gather (4KB) -> 16 MFMA -> 16 atomics.
// A: row=lane&15, k=(lane>>4)*8+i ; B: col=lane&15, same k ;
// C: col=lane&15, row=(lane>>4)*4+reg  (m89-verified)
// grid: (G, R_LEVELS, 2)  block 256 (4 waves)
// ---------------------------------------------------------------------------
__global__ __launch_bounds__(256)
void edge_mfma_pre(const int* __restrict__ u_idx,
                   const int* __restrict__ v_idx,
                   const unsigned short* __restrict__ Xn_u,
                   const unsigned short* __restrict__ Xn_v,
                   const unsigned short* __restrict__ WcT_u,
                   const unsigned short* __restrict__ WcT_v,
                   float* __restrict__ out) {
    const int r    = blockIdx.y;
    const bool toUser = (blockIdx.z == 0);
    const int lane = threadIdx.x & 63;
    const int wave = threadIdx.x >> 6;
    const int m    = lane & 15;
    const int g    = lane >> 4;

    const int* dI = (toUser ? u_idx : v_idx) + (size_t)r * NEDGE;
    const int* sI = (toUser ? v_idx : u_idx) + (size_t)r * NEDGE;
    const unsigned short* Xn  = toUser ? Xn_v : Xn_u;
    const unsigned short* WcT = (toUser ? WcT_u : WcT_v) + (size_t)r * OUT_DIM * IN_DIM;
    float* outp = out + (toUser ? 0 : (size_t)NUM_USERS * OUT_DIM);

    s16x8 bfrag[4][4];
#pragma unroll
    for (int nt = 0; nt < 4; ++nt)
#pragma unroll
        for (int ks = 0; ks < 4; ++ks)
            bfrag[nt][ks] = *reinterpret_cast<const s16x8*>(
                WcT + ((size_t)(nt * 16 + m) * IN_DIM + ks * 32 + g * 8));

    const int wid     = blockIdx.x * 4 + wave;
    const int wstride = gridDim.x * 4;
    constexpr int NCHUNK = NEDGE / 16;   // 18750

    for (int c = wid; c < NCHUNK; c += wstride) {
        const int e0 = c * 16;
        const int sS = sI[e0 + m];                              // row for edge m
        const int4 dd4 = *reinterpret_cast<const int4*>(dI + e0 + g * 4);
        const unsigned short* xrow = Xn + (size_t)sS * IN_DIM;

        s16x8 afrag[4];
#pragma unroll
        for (int ks = 0; ks < 4; ++ks)
            afrag[ks] = *reinterpret_cast<const s16x8*>(xrow + ks * 32 + g * 8);

        const int dd[4] = {dd4.x, dd4.y, dd4.z, dd4.w};
#pragma unroll
        for (int nt = 0; nt < 4; ++nt) {
            f32x4 acc = {0.f, 0.f, 0.f, 0.f};
#pragma unroll
            for (int ks = 0; ks < 4; ++ks)
                acc = __builtin_amdgcn_mfma_f32_16x16x32_bf16(
                    afrag[ks], bfrag[nt][ks], acc, 0, 0, 0);
#pragma unroll
            for (int i = 0; i < 4; ++i)
                atomicAdd(outp + (size_t)dd[i] * OUT_DIM + nt * 16 + m, acc[i]);
        }
    }
}

// ---------------------------------------------------------------------------
// Kernel B (legacy fallback, ws too small): round-5 version, norm in-loop
// ---------------------------------------------------------------------------
__global__ __launch_bounds__(256)
void edge_mfma(const int* __restrict__ u_idx, const int* __restrict__ v_idx,
               const float* __restrict__ deg_user, const float* __restrict__ deg_item,
               const float* __restrict__ X_u, const float* __restrict__ X_v,
               const unsigned short* __restrict__ WcT_u,
               const unsigned short* __restrict__ WcT_v,
               float* __restrict__ out) {
    const int r    = blockIdx.y;
    const bool toUser = (blockIdx.z == 0);
    const int lane = threadIdx.x & 63;
    const int wave = threadIdx.x >> 6;
    const int m    = lane & 15;
    const int g    = lane >> 4;

    const int*   dI   = (toUser ? u_idx : v_idx) + (size_t)r * NEDGE;
    const int*   sI   = (toUser ? v_idx : u_idx) + (size_t)r * NEDGE;
    const float* degD = toUser ? deg_user : deg_item;
    const float* degS = toUser ? deg_item : deg_user;
    const float* Xs   = toUser ? X_v : X_u;
    const unsigned short* WcT = (toUser ? WcT_u : WcT_v) + (size_t)r * OUT_DIM * IN_DIM;
    float* outp = out + (toUser ? 0 : (size_t)NUM_USERS * OUT_DIM);

    s16x8 bfrag[4][4];
#pragma unroll
    for (int nt = 0; nt < 4; ++nt)
#pragma unroll
        for (int ks = 0; ks < 4; ++ks)
            bfrag[nt][ks] = *reinterpret_cast<const s16x8*>(
                WcT + ((size_t)(nt * 16 + m) * IN_DIM + ks * 32 + g * 8));

    const int wid     = blockIdx.x * 4 + wave;
    const int wstride = gridDim.x * 4;
    constexpr int NCHUNK = NEDGE / 16;

    for (int c = wid; c < NCHUNK; c += wstride) {
        const int e0 = c * 16;
        const int sS  = sI[e0 + m];
        const int dDm = dI[e0 + m];
        const float norm = 1.0f / (sqrtf(fmaxf(degD[dDm], EPSC)) *
                                   sqrtf(fmaxf(degS[sS],  EPSC)));
        const float* xrow = Xs + (size_t)sS * IN_DIM;

        s16x8 afrag[4];
#pragma unroll
        for (int ks = 0; ks < 4; ++ks) {
            const float4 q0 = *reinterpret_cast<const float4*>(xrow + ks * 32 + g * 8);
            const float4 q1 = *reinterpret_cast<const float4*>(xrow + ks * 32 + g * 8 + 4);
            s16x8 av;
            av[0] = (short)f2bf(q0.x * norm); av[1] = (short)f2bf(q0.y * norm);
            av[2] = (short)f2bf(q0.z * norm); av[3] = (short)f2bf(q0.w * norm);
            av[4] = (short)f2bf(q1.x * norm); av[5] = (short)f2bf(q1.y * norm);
            av[6] = (short)f2bf(q1.z * norm); av[7] = (short)f2bf(q1.w * norm);
            afrag[ks] = av;
        }

        int dd[4];
#pragma unroll
        for (int i = 0; i < 4; ++i) dd[i] = dI[e0 + g * 4 + i];

#pragma unroll
        for (int nt = 0; nt < 4; ++nt) {
            f32x4 acc = {0.f, 0.f, 0.f, 0.f};
#pragma unroll
            for (int ks = 0; ks < 4; ++ks)
                acc = __builtin_amdgcn_mfma_f32_16x16x32_bf16(
                    afrag[ks], bfrag[nt][ks], acc, 0, 0, 0);
#pragma unroll
            for (int i = 0; i < 4; ++i)
                atomicAdd(outp + (size_t)dd[i] * OUT_DIM + nt * 16 + m, acc[i]);
        }
    }
}

// ---------------------------------------------------------------------------
// Epilogues
// ---------------------------------------------------------------------------
__global__ void bias_relu_scaled(float* __restrict__ out,
                                 const float* __restrict__ b_u,
                                 const float* __restrict__ b_v,
                                 const float* __restrict__ rsq_u,
                                 const float* __restrict__ rsq_v) {
    const size_t i = (size_t)blockIdx.x * 256 + threadIdx.x;
    constexpr size_t UOUT = (size_t)NUM_USERS * OUT_DIM;
    constexpr size_t TOT  = UOUT + (size_t)NUM_ITEMS * OUT_DIM;
    if (i < UOUT) {
        out[i] = fmaxf(fmaf(out[i], rsq_u[i >> 6], b_u[i & 63]), 0.f);
    } else if (i < TOT) {
        const size_t k = i - UOUT;
        out[i] = fmaxf(fmaf(out[i], rsq_v[k >> 6], b_v[i & 63]), 0.f);
    }
}

__global__ void bias_relu(float* __restrict__ out,
                          const float* __restrict__ b_u,
                          const float* __restrict__ b_v) {
    const size_t i = (size_t)blockIdx.x * 256 + threadIdx.x;
    constexpr size_t UOUT = (size_t)NUM_USERS * OUT_DIM;
    constexpr size_t TOT  = UOUT + (size_t)NUM_ITEMS * OUT_DIM;
    if (i < TOT) {
        const float b = (i < UOUT) ? b_u[i & 63] : b_v[i & 63];
        out[i] = fmaxf(out[i] + b, 0.f);
    }
}

// ---------------------------------------------------------------------------
extern "C" void kernel_launch(void* const* d_in, const int* in_sizes, int n_in,
                              void* d_out, int out_size, void* d_ws, size_t ws_size,
                              hipStream_t stream) {
    const int*   u_idx    = (const int*)  d_in[0];
    const int*   v_idx    = (const int*)  d_in[1];
    const float* deg_user = (const float*)d_in[2];
    const float* deg_item = (const float*)d_in[3];
    const float* X_u      = (const float*)d_in[4];
    const float* X_v      = (const float*)d_in[5];
    const float* W_i2u    = (const float*)d_in[6];
    const float* W_u2i    = (const float*)d_in[7];
    const float* W_out_u  = (const float*)d_in[8];
    const float* b_out_u  = (const float*)d_in[9];
    const float* W_out_i  = (const float*)d_in[10];
    const float* b_out_i  = (const float*)d_in[11];

    float* out = (float*)d_out;

    // workspace layout (bytes)
    constexpr size_t WCT_ELEMS = (size_t)R_LEVELS * OUT_DIM * IN_DIM;   // 40960
    char* wsb = (char*)d_ws;
    unsigned short* WcT_u = (unsigned short*)wsb;                       // 81920 B
    unsigned short* WcT_v = WcT_u + WCT_ELEMS;                          // 81920 B
    float* rsq_u = (float*)(wsb + 163840);                              // 400000 B
    float* rsq_v = (float*)(wsb + 563840);                              // 200000 B
    unsigned short* Xn_u = (unsigned short*)(wsb + 763840);             // 25.6 MB
    unsigned short* Xn_v = (unsigned short*)(wsb + 763840 + 25600000);  // 12.8 MB
    constexpr size_t WS_NEED = 763840 + 25600000 + 12800000;            // ~39.2 MB
    const bool fast = (ws_size >= WS_NEED);

    hipMemsetAsync(d_out, 0, (size_t)out_size * sizeof(float), stream);

    fuse_weights<<<dim3(R_LEVELS * IN_DIM, 2), 64, 0, stream>>>(
        W_i2u, W_u2i, W_out_u, W_out_i, WcT_u, WcT_v);

    if (fast) {
        prescale_rows<<<(NUM_USERS + 3) / 4, 256, 0, stream>>>(
            X_u, deg_user, Xn_u, rsq_u, NUM_USERS);
        prescale_rows<<<(NUM_ITEMS + 3) / 4, 256, 0, stream>>>(
            X_v, deg_item, Xn_v, rsq_v, NUM_ITEMS);

        edge_mfma_pre<<<dim3(384, R_LEVELS, 2), 256, 0, stream>>>(
            u_idx, v_idx, Xn_u, Xn_v, WcT_u, WcT_v, out);

        const size_t total = (size_t)NUM_USERS * OUT_DIM + (size_t)NUM_ITEMS * OUT_DIM;
        bias_relu_scaled<<<(int)((total + 255) / 256), 256, 0, stream>>>(
            out, b_out_u, b_out_i, rsq_u, rsq_v);
    } else {
        edge_mfma<<<dim3(384, R_LEVELS, 2), 256, 0, stream>>>(
            u_idx, v_idx, deg_user, deg_item, X_u, X_v, WcT_u, WcT_v, out);

        const size_t total = (size_t)NUM_USERS * OUT_DIM + (size_t)NUM_ITEMS * OUT_DIM;
        bias_relu<<<(int)((total + 255) / 256), 256, 0, stream>>>(out, b_out_u, b_out_i);
    }
}

// Round 9
// 779.272 us; speedup vs baseline: 2.2004x; 1.0266x over previous
//
#include <hip/hip_runtime.h>
#include <hip/hip_bf16.h>

#define NUM_USERS 100000
#define NUM_ITEMS 50000
#define IN_DIM 128
#define HID_DIM 256
#define OUT_DIM 64
#define R_LEVELS 5
#define NEDGE 300000
#define EPSC 1e-10f

#define NE2   (R_LEVELS * NEDGE)          // 1,500,000 edges per direction
#define BIN_U (R_LEVELS * NUM_USERS)      // 500,000 user bins
#define BIN_V (R_LEVELS * NUM_ITEMS)      // 250,000 item bins
#define NBIN  (BIN_U + BIN_V)             // 750,000
#define NLIST (2 * NE2)                   // 3,000,000 list slots
#define SCAN_BLK  2048
#define SCAN_NBLK ((NBIN + SCAN_BLK - 1) / SCAN_BLK)   // 367

typedef float f32x4 __attribute__((ext_vector_type(4)));
typedef short s16x8 __attribute__((ext_vector_type(8)));

static __device__ __forceinline__ unsigned short f2bf(float f) {
    __hip_bfloat16 h = __float2bfloat16(f);   // RNE
    return *reinterpret_cast<unsigned short*>(&h);
}

// ---------------------------------------------------------------------------
// Kernel A: WcT[r][n][k] = (W1[r] @ Wout)^T in bf16 (B-fragment = one 16B load)
// ---------------------------------------------------------------------------
__global__ void fuse_weights(const float* __restrict__ W_i2u,
                             const float* __restrict__ W_u2i,
                             const float* __restrict__ Wout_u,
                             const float* __restrict__ Wout_i,
                             unsigned short* __restrict__ WcT_u,
                             unsigned short* __restrict__ WcT_v) {
    const int rk = blockIdx.x;          // r*128 + k
    const int r  = rk >> 7;
    const int k  = rk & 127;
    const int j  = threadIdx.x;         // 0..63
    const bool userDir = (blockIdx.y == 0);
    const float* w1   = (userDir ? W_i2u : W_u2i) + (size_t)rk * HID_DIM;
    const float* wout = (userDir ? Wout_u : Wout_i);
    float acc = 0.f;
    for (int h = 0; h < HID_DIM; ++h)
        acc = fmaf(w1[h], wout[h * OUT_DIM + j], acc);
    unsigned short* dst = (userDir ? WcT_u : WcT_v);
    dst[(((size_t)r * OUT_DIM + j) * IN_DIM) + k] = f2bf(acc);
}

// ---------------------------------------------------------------------------
// Kernel P: Xn[row] = bf16( X[row] * rsq(deg[row]) ), plus rsq[] for epilogue
// ---------------------------------------------------------------------------
__global__ void prescale_rows(const float* __restrict__ X,
                              const float* __restrict__ deg,
                              unsigned short* __restrict__ Xn,
                              float* __restrict__ rsq, int nrows) {
    const int row = blockIdx.x * 4 + (threadIdx.x >> 6);
    if (row >= nrows) return;
    const int lane = threadIdx.x & 63;
    const float r = 1.0f / sqrtf(fmaxf(deg[row], EPSC));
    if (lane == 0) rsq[row] = r;
    const float2 x = ((const float2*)(X + (size_t)row * IN_DIM))[lane];
    const unsigned int packed = (unsigned int)f2bf(x.x * r) |
                                ((unsigned int)f2bf(x.y * r) << 16);
    ((unsigned int*)(Xn + (size_t)row * IN_DIM))[lane] = packed;
}

// ---------------------------------------------------------------------------
// CSR build: histogram -> 2-level exclusive scan -> fill
// bins: user  bin = r*NUM_USERS + u          (stores v)
//       item  bin = BIN_U + r*NUM_ITEMS + v  (stores u)
// ---------------------------------------------------------------------------
__global__ void hist_kernel(const int* __restrict__ u_idx,
                            const int* __restrict__ v_idx,
                            int* __restrict__ cnt) {
    const int e = blockIdx.x * 256 + threadIdx.x;
    if (e >= NE2) return;
    const int r = e / NEDGE;
    atomicAdd(&cnt[r * NUM_USERS + u_idx[e]], 1);
    atomicAdd(&cnt[BIN_U + r * NUM_ITEMS + v_idx[e]], 1);
}

__global__ void scan_local(const int* __restrict__ cnt,
                           int* __restrict__ off,
                           int* __restrict__ blksum) {
    __shared__ int lds[256];
    const int tid  = threadIdx.x;
    const int base = blockIdx.x * SCAN_BLK + tid * 8;
    int v[8]; int s = 0;
#pragma unroll
    for (int i = 0; i < 8; ++i) {
        const int idx = base + i;
        v[i] = (idx < NBIN) ? cnt[idx] : 0;
        s += v[i];
    }
    lds[tid] = s;
    __syncthreads();
    for (int d = 1; d < 256; d <<= 1) {
        int t = (tid >= d) ? lds[tid - d] : 0;
        __syncthreads();
        lds[tid] += t;
        __syncthreads();
    }
    const int inc = lds[tid];
    if (tid == 255) blksum[blockIdx.x] = inc;   // block total
    int run = inc - s;                          // exclusive prefix
#pragma unroll
    for (int i = 0; i < 8; ++i) {
        const int idx = base + i;
        if (idx < NBIN) off[idx] = run;
        run += v[i];
    }
}

__global__ void scan_top(int* __restrict__ blksum) {
    __shared__ int lds[512];
    const int tid = threadIdx.x;
    const int v = (tid < SCAN_NBLK) ? blksum[tid] : 0;
    lds[tid] = v;
    __syncthreads();
    for (int d = 1; d < 512; d <<= 1) {
        int t = (tid >= d) ? lds[tid - d] : 0;
        __syncthreads();
        lds[tid] += t;
        __syncthreads();
    }
    if (tid < SCAN_NBLK) blksum[tid] = lds[tid] - v;   // exclusive
}

__global__ void scan_add(int* __restrict__ off, int* __restrict__ cur,
                         const int* __restrict__ blksum) {
    const int tid  = threadIdx.x;
    const int base = blockIdx.x * SCAN_BLK + tid * 8;
    const int boff = blksum[blockIdx.x];
#pragma unroll
    for (int i = 0; i < 8; ++i) {
        const int idx = base + i;
        if (idx < NBIN) {
            const int o = off[idx] + boff;
            off[idx] = o;
            cur[idx] = o;
        }
    }
    if (blockIdx.x == 0 && tid == 0) off[NBIN] = NLIST;   // sentinel
}

__global__ void fill_kernel(const int* __restrict__ u_idx,
                            const int* __restrict__ v_idx,
                            int* __restrict__ cur, int* __restrict__ list) {
    const int e = blockIdx.x * 256 + threadIdx.x;
    if (e >= NE2) return;
    const int r = e / NEDGE;
    const int u = u_idx[e], v = v_idx[e];
    const int pu = atomicAdd(&cur[r * NUM_USERS + u], 1);
    list[pu] = v;
    const int pv = atomicAdd(&cur[BIN_U + r * NUM_ITEMS + v], 1);
    list[pv] = u;
}

// ---------------------------------------------------------------------------
// Gather-compute: wave owns 16 dests. Per r: sum bin's Xn rows in f32 regs
// (lane (g,m): dest-row m, k-slice ks*32+g*8..+7), cvt -> A-frag, 16 MFMA
// accumulating C across r. Epilogue in-register: *rsq_d + bias, ReLU, store
// once (no atomics, no memset). C layout: col=lane&15, row=(lane>>4)*4+reg.
// ---------------------------------------------------------------------------
__global__ __launch_bounds__(256)
void gather_mfma(const int* __restrict__ off, const int* __restrict__ list,
                 const unsigned short* __restrict__ Xn_src,
                 const unsigned short* __restrict__ WcT,
                 const float* __restrict__ rsq_d,
                 const float* __restrict__ bias,
                 float* __restrict__ outp, int nd, int bin_base) {
    const int lane  = threadIdx.x & 63;
    const int wave  = threadIdx.x >> 6;
    const int m     = lane & 15;
    const int g     = lane >> 4;
    const int dbase = blockIdx.x * 64 + wave * 16;
    const int dg    = dbase + m;        // dest whose edge list this lane reads

    f32x4 accC[4] = {{0.f,0.f,0.f,0.f},{0.f,0.f,0.f,0.f},
                     {0.f,0.f,0.f,0.f},{0.f,0.f,0.f,0.f}};

    for (int r = 0; r < R_LEVELS; ++r) {
        int start = 0, len = 0;
        if (dg < nd) {
            const int bin = bin_base + r * nd + dg;
            start = off[bin];
            len   = off[bin + 1] - start;
        }
        float s[4][8];
#pragma unroll
        for (int ks = 0; ks < 4; ++ks)
#pragma unroll
            for (int i = 0; i < 8; ++i) s[ks][i] = 0.f;

        for (int t = 0; ; ++t) {
            const bool act = (t < len);
            if (!__any((int)act)) break;
            if (act) {
                const unsigned short* row =
                    Xn_src + (size_t)list[start + t] * IN_DIM;
#pragma unroll
                for (int ks = 0; ks < 4; ++ks) {
                    const s16x8 w = *reinterpret_cast<const s16x8*>(
                        row + ks * 32 + g * 8);
#pragma unroll
                    for (int i = 0; i < 8; ++i) {
                        const unsigned int bits =
                            ((unsigned int)(unsigned short)w[i]) << 16;
                        s[ks][i] += __uint_as_float(bits);
                    }
                }
            }
        }

        s16x8 af[4];
#pragma unroll
        for (int ks = 0; ks < 4; ++ks)
#pragma unroll
            for (int i = 0; i < 8; ++i)
                af[ks][i] = (short)f2bf(s[ks][i]);

        const unsigned short* Wr = WcT + (size_t)r * OUT_DIM * IN_DIM;
#pragma unroll
        for (int nt = 0; nt < 4; ++nt) {
#pragma unroll
            for (int ks = 0; ks < 4; ++ks) {
                const s16x8 bf = *reinterpret_cast<const s16x8*>(
                    Wr + (size_t)(nt * 16 + m) * IN_DIM + ks * 32 + g * 8);
                accC[nt] = __builtin_amdgcn_mfma_f32_16x16x32_bf16(
                    af[ks], bf, accC[nt], 0, 0, 0);
            }
        }
    }

#pragma unroll
    for (int i = 0; i < 4; ++i) {
        const int d = dbase + g * 4 + i;
        if (d < nd) {
            const float rs = rsq_d[d];
#pragma unroll
            for (int nt = 0; nt < 4; ++nt)
                outp[(size_t)d * OUT_DIM + nt * 16 + m] =
                    fmaxf(fmaf(accC[nt][i], rs, bias[nt * 16 + m]), 0.f);
        }
    }
}

// ---------------------------------------------------------------------------
// Fallback path (ws too small for CSR): round-6 scatter-atomic kernels
// ---------------------------------------------------------------------------
__global__ __launch_bounds__(256)
void edge_mfma_pre(const int* __restrict__ u_idx,
                   const int* __restrict__ v_idx,
                   const unsigned short* __restrict__ Xn_u,
                   const unsigned short* __restrict__ Xn_v,
                   const unsigned short* __restrict__ WcT_u,
                   const unsigned short* __restrict__ WcT_v,
                   float* __restrict__ out) {
    const int r    = blockIdx.y;
    const bool toUser = (blockIdx.z == 0);
    const int lane = threadIdx.x & 63;
    const int wave = threadIdx.x >> 6;
    const int m    = lane & 15;
    const int g    = lane >> 4;

    const int* dI = (toUser ? u_idx : v_idx) + (size_t)r * NEDGE;
    const int* sI = (toUser ? v_idx : u_idx) + (size_t)r * NEDGE;
    const unsigned short* Xn  = toUser ? Xn_v : Xn_u;
    const unsigned short* WcT = (toUser ? WcT_u : WcT_v) + (size_t)r * OUT_DIM * IN_DIM;
    float* outp = out + (toUser ? 0 : (size_t)NUM_USERS * OUT_DIM);

    s16x8 bfrag[4][4];
#pragma unroll
    for (int nt = 0; nt < 4; ++nt)
#pragma unroll
        for (int ks = 0; ks < 4; ++ks)
            bfrag[nt][ks] = *reinterpret_cast<const s16x8*>(
                WcT + ((size_t)(nt * 16 + m) * IN_DIM + ks * 32 + g * 8));

    const int wid     = blockIdx.x * 4 + wave;
    const int wstride = gridDim.x * 4;
    constexpr int NCHUNK = NEDGE / 16;

    for (int c = wid; c < NCHUNK; c += wstride) {
        const int e0 = c * 16;
        const int sS = sI[e0 + m];
        const int4 dd4 = *reinterpret_cast<const int4*>(dI + e0 + g * 4);
        const unsigned short* xrow = Xn + (size_t)sS * IN_DIM;

        s16x8 afrag[4];
#pragma unroll
        for (int ks = 0; ks < 4; ++ks)
            afrag[ks] = *reinterpret_cast<const s16x8*>(xrow + ks * 32 + g * 8);

        const int dd[4] = {dd4.x, dd4.y, dd4.z, dd4.w};
#pragma unroll
        for (int nt = 0; nt < 4; ++nt) {
            f32x4 acc = {0.f, 0.f, 0.f, 0.f};
#pragma unroll
            for (int ks = 0; ks < 4; ++ks)
                acc = __builtin_amdgcn_mfma_f32_16x16x32_bf16(
                    afrag[ks], bfrag[nt][ks], acc, 0, 0, 0);
#pragma unroll
            for (int i = 0; i < 4; ++i)
                atomicAdd(outp + (size_t)dd[i] * OUT_DIM + nt * 16 + m, acc[i]);
        }
    }
}

__global__ void bias_relu_scaled(float* __restrict__ out,
                                 const float* __restrict__ b_u,
                                 const float* __restrict__ b_v,
                                 const float* __restrict__ rsq_u,
                                 const float* __restrict__ rsq_v) {
    const size_t i = (size_t)blockIdx.x * 256 + threadIdx.x;
    constexpr size_t UOUT = (size_t)NUM_USERS * OUT_DIM;
    constexpr size_t TOT  = UOUT + (size_t)NUM_ITEMS * OUT_DIM;
    if (i < UOUT) {
        out[i] = fmaxf(fmaf(out[i], rsq_u[i >> 6], b_u[i & 63]), 0.f);
    } else if (i < TOT) {
        const size_t k = i - UOUT;
        out[i] = fmaxf(fmaf(out[i], rsq_v[k >> 6], b_v[i & 63]), 0.f);
    }
}

// ---------------------------------------------------------------------------
extern "C" void kernel_launch(void* const* d_in, const int* in_sizes, int n_in,
                              void* d_out, int out_size, void* d_ws, size_t ws_size,
                              hipStream_t stream) {
    const int*   u_idx    = (const int*)  d_in[0];
    const int*   v_idx    = (const int*)  d_in[1];
    const float* deg_user = (const float*)d_in[2];
    const float* deg_item = (const float*)d_in[3];
    const float* X_u      = (const float*)d_in[4];
    const float* X_v      = (const float*)d_in[5];
    const float* W_i2u    = (const float*)d_in[6];
    const float* W_u2i    = (const float*)d_in[7];
    const float* W_out_u  = (const float*)d_in[8];
    const float* b_out_u  = (const float*)d_in[9];
    const float* W_out_i  = (const float*)d_in[10];
    const float* b_out_i  = (const float*)d_in[11];

    float* out = (float*)d_out;
    char*  wsb = (char*)d_ws;

    // ---- workspace layout (all 64B-aligned) ----
    size_t o = 0;
    unsigned short* WcT_u = (unsigned short*)(wsb + o); o += 81920;      // [5][64][128] bf16
    unsigned short* WcT_v = (unsigned short*)(wsb + o); o += 81920;
    float* rsq_u = (float*)(wsb + o); o += 400000;
    float* rsq_v = (float*)(wsb + o); o += 200000;
    unsigned short* Xn_u = (unsigned short*)(wsb + o); o += 25600000;    // [100K][128] bf16
    unsigned short* Xn_v = (unsigned short*)(wsb + o); o += 12800000;    // [50K][128] bf16
    const size_t WS_FAST = o;                                            // 39,163,840
    int* cnt    = (int*)(wsb + o); o += (size_t)NBIN * 4;                // 3,000,000
    int* off    = (int*)(wsb + o); o += 3000064;                         // NBIN+1, padded
    int* cur    = (int*)(wsb + o); o += (size_t)NBIN * 4;
    int* blksum = (int*)(wsb + o); o += 2048;                            // 512 ints
    int* list   = (int*)(wsb + o); o += (size_t)NLIST * 4;               // 12,000,000
    const size_t WS_CSR = o;                                             // ~60.2 MB
    const bool csr = (ws_size >= WS_CSR);
    (void)WS_FAST;

    // shared preprocessing
    fuse_weights<<<dim3(R_LEVELS * IN_DIM, 2), 64, 0, stream>>>(
        W_i2u, W_u2i, W_out_u, W_out_i, WcT_u, WcT_v);
    prescale_rows<<<(NUM_USERS + 3) / 4, 256, 0, stream>>>(
        X_u, deg_user, Xn_u, rsq_u, NUM_USERS);
    prescale_rows<<<(NUM_ITEMS + 3) / 4, 256, 0, stream>>>(
        X_v, deg_item, Xn_v, rsq_v, NUM_ITEMS);

    if (csr) {
        // ---- CSR build ----
        hipMemsetAsync(cnt, 0, (size_t)NBIN * 4, stream);
        hist_kernel<<<(NE2 + 255) / 256, 256, 0, stream>>>(u_idx, v_idx, cnt);
        scan_local<<<SCAN_NBLK, 256, 0, stream>>>(cnt, off, blksum);
        scan_top<<<1, 512, 0, stream>>>(blksum);
        scan_add<<<SCAN_NBLK, 256, 0, stream>>>(off, cur, blksum);
        fill_kernel<<<(NE2 + 255) / 256, 256, 0, stream>>>(u_idx, v_idx, cur, list);

        // ---- gather-compute, one store per output element ----
        gather_mfma<<<(NUM_USERS + 63) / 64, 256, 0, stream>>>(
            off, list, Xn_v, WcT_u, rsq_u, b_out_u, out, NUM_USERS, 0);
        gather_mfma<<<(NUM_ITEMS + 63) / 64, 256, 0, stream>>>(
            off, list, Xn_u, WcT_v, rsq_v, b_out_i,
            out + (size_t)NUM_USERS * OUT_DIM, NUM_ITEMS, BIN_U);
    } else {
        // ---- fallback: round-6 scatter-atomic path ----
        hipMemsetAsync(d_out, 0, (size_t)out_size * sizeof(float), stream);
        edge_mfma_pre<<<dim3(384, R_LEVELS, 2), 256, 0, stream>>>(
            u_idx, v_idx, Xn_u, Xn_v, WcT_u, WcT_v, out);
        const size_t total = (size_t)NUM_USERS * OUT_DIM + (size_t)NUM_ITEMS * OUT_DIM;
        bias_relu_scaled<<<(int)((total + 255) / 256), 256, 0, stream>>>(
            out, b_out_u, b_out_i, rsq_u, rsq_v);
    }
}